// Round 2
// baseline (270.764 us; speedup 1.0000x reference)
//
#include <hip/hip_runtime.h>
#include <hip/hip_bf16.h>

#define NQ 6

typedef __attribute__((ext_vector_type(8))) short short8;
typedef __attribute__((ext_vector_type(4))) float floatx4;

// ---------------- ws layout (bytes) ----------------
// U_circ : float2[64*64]        @ 0        (32768 B)
// Mq     : float[18]            @ 32768
// cq     : float[3]             @ 32840
// W1bf   : short[64*2048]       @ 36864    (262144 B)
#define WS_MQ_F   8192        // float offset of Mq
#define WS_CQ_F   (8192+18)
#define WS_W1BF_B 36864

// ============ K0: prep — U_circ columns, Mq/cq, W1->bf16 ============
__global__ __launch_bounds__(64) void prep_kernel(
    const float* __restrict__ qw, int n_layers,
    const float* __restrict__ W1, const float* __restrict__ Wq,
    const float* __restrict__ bq, const float* __restrict__ Wf,
    const float* __restrict__ bf, float* __restrict__ ws_f,
    short* __restrict__ w1bf)
{
    const int blk  = blockIdx.x;
    const int lane = threadIdx.x;

    if (blk == 0) {
        // Mq[j][w] = sum_m Wf[j][64+m] * Wq[m][w];  cq[j] = sum_m Wf[j][64+m]*bq[m] + bf[j]
        if (lane < 18) {
            int j = lane / 6, wi = lane % 6;
            float s = 0.f;
            for (int m = 0; m < 16; ++m) s += Wf[j*80 + 64 + m] * Wq[m*6 + wi];
            ws_f[WS_MQ_F + lane] = s;
        } else if (lane < 21) {
            int j = lane - 18;
            float s = bf[j];
            for (int m = 0; m < 16; ++m) s += Wf[j*80 + 64 + m] * bq[m];
            ws_f[WS_CQ_F + j] = s;
        }
    } else if (blk <= 64) {
        // U_circ column j: amplitudes-in-lanes, one wave
        const int j = blk - 1;
        float re = (lane == j) ? 1.f : 0.f;
        float im = 0.f;
        for (int l = 0; l < n_layers; ++l) {
            for (int w = 0; w < NQ; ++w) {
                const float* g = qw + (l*NQ + w)*3;
                float phi = g[0], th = g[1], om = g[2];
                float c, s;  __sincosf(0.5f*th, &s, &c);
                float sa, ca; __sincosf(0.5f*(phi+om), &sa, &ca);
                float sb, cb; __sincosf(0.5f*(phi-om), &sb, &cb);
                // U00=c(ca-i sa)  U01=-s(cb+i sb)  U10=s(cb-i sb)  U11=c(ca+i sa)
                float u00r =  c*ca, u00i = -c*sa;
                float u01r = -s*cb, u01i = -s*sb;
                float u10r =  s*cb, u10i = -s*sb;
                float u11r =  c*ca, u11i =  c*sa;
                int p = 5 - w, mask = 1 << p;
                float pre = __shfl_xor(re, mask, 64);
                float pim = __shfl_xor(im, mask, 64);
                int b = (lane >> p) & 1;
                float mr = b ? u11r : u00r, mi = b ? u11i : u00i;
                float pr = b ? u10r : u01r, pi = b ? u10i : u01i;
                float nre = mr*re - mi*im + pr*pre - pi*pim;
                float nim = mr*im + mi*re + pr*pim + pi*pre;
                re = nre; im = nim;
            }
            int r = l % (NQ-1) + 1;
            for (int w = 0; w < NQ; ++w) {
                int tgt = (w + r) % NQ;
                int tmask = 1 << (5 - tgt);
                float pre = __shfl_xor(re, tmask, 64);
                float pim = __shfl_xor(im, tmask, 64);
                int cs = (lane >> (5 - w)) & 1;
                re = cs ? pre : re;
                im = cs ? pim : im;
            }
        }
        ws_f[(lane*64 + j)*2 + 0] = re;   // U[i=lane][j].re
        ws_f[(lane*64 + j)*2 + 1] = im;
    } else {
        // W1 fp32 -> bf16 (same [n][k] row-major layout), blocks 65..320
        int idx = (blk - 65)*512 + lane*8;
        if (idx < 64*2048) {
            float4 a0 = *(const float4*)(W1 + idx);
            float4 a1 = *(const float4*)(W1 + idx + 4);
            union { short8 v; __hip_bfloat162 h[4]; } u;
            float2 f;
            f.x=a0.x; f.y=a0.y; u.h[0] = __float22bfloat162_rn(f);
            f.x=a0.z; f.y=a0.w; u.h[1] = __float22bfloat162_rn(f);
            f.x=a1.x; f.y=a1.y; u.h[2] = __float22bfloat162_rn(f);
            f.x=a1.z; f.y=a1.w; u.h[3] = __float22bfloat162_rn(f);
            *(short8*)(w1bf + idx) = u.v;
        }
    }
}

// ============ K1: fused quantum + GEMM + ReLU + 3-wide head ============
// grid B/64, 1024 threads (16 waves = 4 waves/SIMD for latency hiding).
// Phase Q: 16 waves each handle 4 U-rows. Phase G: wave (wr=t>>2, wc=t&3)
// computes a 16-row x 16-col quadrant, 1 MFMA per k-step, prefetch-1.
__global__ __launch_bounds__(1024) void fused_kernel(
    const float* __restrict__ xq, const float2* __restrict__ U,
    const float* __restrict__ ws_f,
    const float* __restrict__ xc, const short* __restrict__ w1bf,
    const float* __restrict__ b1, const float* __restrict__ Wf,
    float* __restrict__ out)
{
    const int tid  = threadIdx.x;
    const int lane = tid & 63;
    const int t    = __builtin_amdgcn_readfirstlane((int)(tid >> 6)); // wave 0..15
    const int blk  = blockIdx.x;

    __shared__ float zbuf[16][64][6];
    __shared__ float qres[64][3];
    __shared__ float cl[64][65];

    // ---------- Phase Q: quantum part for this block's 64 rows ----------
    {
        const int b = blk*64 + lane;
        float a[64];
        const float* x = xq + (size_t)b*6;
        a[0] = 1.f;
        #pragma unroll
        for (int q = 0; q < 6; ++q) {
            float c, s; __sincosf(0.5f*x[q], &s, &c);
            const int sz = 1 << q;
            #pragma unroll
            for (int m = sz-1; m >= 0; --m) {
                float v = a[m];
                a[2*m+1] = v*s;
                a[2*m+0] = v*c;
            }
        }

        float zp[6] = {0,0,0,0,0,0};
        const float2* Urow = U + t*4*64;   // wave-uniform -> scalar loads
        for (int ii = 0; ii < 4; ++ii) {
            float rr = 0.f, ri = 0.f;
            #pragma unroll
            for (int j = 0; j < 64; ++j) {
                float2 u = Urow[ii*64 + j];
                rr += u.x * a[j];
                ri += u.y * a[j];
            }
            float p = rr*rr + ri*ri;
            int i = t*4 + ii;
            #pragma unroll
            for (int w = 0; w < 6; ++w) zp[w] += ((i >> (5-w)) & 1) ? -p : p;
        }
        #pragma unroll
        for (int w = 0; w < 6; ++w) zbuf[t][lane][w] = zp[w];
    }
    __syncthreads();
    if (t == 0) {
        float z[6];
        #pragma unroll
        for (int w = 0; w < 6; ++w) {
            float s = 0.f;
            #pragma unroll
            for (int sbi = 0; sbi < 16; ++sbi) s += zbuf[sbi][lane][w];
            z[w] = s;
        }
        #pragma unroll
        for (int j = 0; j < 3; ++j) {
            float v = ws_f[WS_CQ_F + j];
            #pragma unroll
            for (int w = 0; w < 6; ++w) v += ws_f[WS_MQ_F + j*6 + w] * z[w];
            qres[lane][j] = v;
        }
    }
    // qres read only after the epilogue __syncthreads -> no extra sync.

    // ---------- Phase G: wave (wr,wc) -> rows [wr*16,+16) x cols [wc*16,+16) ----------
    const int wr = t >> 2, wc = t & 3;
    const int row  = blk*64 + wr*16 + (lane & 15);  // A fragment: m = lane&15
    const int koff = (lane >> 4) * 8;               // k = (lane>>4)*8 + j

    const float* ap = xc + (size_t)row*2048 + koff;
    const short* bp = w1bf + (wc*16 + (lane & 15))*2048 + koff;

    floatx4 acc = {0,0,0,0};

    // prologue loads (k-step 0)
    float4 a0 = *(const float4*)ap;
    float4 a1 = *(const float4*)(ap + 4);
    short8 bv = *(const short8*)bp;

    #pragma unroll 4
    for (int kk = 1; kk < 64; ++kk) {
        // issue next-iteration loads BEFORE consuming current registers
        float4 na0 = *(const float4*)(ap + kk*32);
        float4 na1 = *(const float4*)(ap + kk*32 + 4);
        short8 nbv = *(const short8*)(bp + kk*32);

        union { short8 v; __hip_bfloat162 h[4]; } af;
        float2 f;
        f.x=a0.x; f.y=a0.y; af.h[0] = __float22bfloat162_rn(f);
        f.x=a0.z; f.y=a0.w; af.h[1] = __float22bfloat162_rn(f);
        f.x=a1.x; f.y=a1.y; af.h[2] = __float22bfloat162_rn(f);
        f.x=a1.z; f.y=a1.w; af.h[3] = __float22bfloat162_rn(f);

        acc = __builtin_amdgcn_mfma_f32_16x16x32_bf16(af.v, bv, acc, 0, 0, 0);

        a0 = na0; a1 = na1; bv = nbv;
    }
    {   // tail (k-step 63's registers)
        union { short8 v; __hip_bfloat162 h[4]; } af;
        float2 f;
        f.x=a0.x; f.y=a0.y; af.h[0] = __float22bfloat162_rn(f);
        f.x=a0.z; f.y=a0.w; af.h[1] = __float22bfloat162_rn(f);
        f.x=a1.x; f.y=a1.y; af.h[2] = __float22bfloat162_rn(f);
        f.x=a1.z; f.y=a1.w; af.h[3] = __float22bfloat162_rn(f);
        acc = __builtin_amdgcn_mfma_f32_16x16x32_bf16(af.v, bv, acc, 0, 0, 0);
    }

    // epilogue: C layout col = wc*16 + (lane&15), row = wr*16 + (lane>>4)*4 + r
    const int rbase = wr*16 + ((lane >> 4) * 4);
    const int c0 = wc*16 + (lane & 15);
    const float bb = b1[c0];
    #pragma unroll
    for (int r = 0; r < 4; ++r)
        cl[rbase + r][c0] = fmaxf(acc[r] + bb, 0.f);
    __syncthreads();

    // final head: wave j (0..2) handles output column j for all 64 rows
    const int rr2 = tid & 63;
    if (t < 3) {
        float v = 0.f;
        #pragma unroll
        for (int col = 0; col < 64; ++col) v += Wf[t*80 + col] * cl[rr2][col];
        int g = blk*64 + rr2;
        out[(size_t)g*3 + t] = v + qres[rr2][t];
    }
}

extern "C" void kernel_launch(void* const* d_in, const int* in_sizes, int n_in,
                              void* d_out, int out_size, void* d_ws, size_t ws_size,
                              hipStream_t stream) {
    const float* xc = (const float*)d_in[0];
    const float* xq = (const float*)d_in[1];
    const float* W1 = (const float*)d_in[2];
    const float* b1 = (const float*)d_in[3];
    const float* qw = (const float*)d_in[4];
    const float* Wq = (const float*)d_in[5];
    const float* bq = (const float*)d_in[6];
    const float* Wf = (const float*)d_in[7];
    const float* bf = (const float*)d_in[8];
    float* out = (float*)d_out;

    const int B = in_sizes[1] / NQ;                 // 16384
    const int n_layers = in_sizes[4] / (NQ * 3);    // 3

    char* ws = (char*)d_ws;
    float*  ws_f  = (float*)ws;
    float2* U     = (float2*)ws;
    short*  w1bf  = (short*)(ws + WS_W1BF_B);

    prep_kernel<<<dim3(321), dim3(64), 0, stream>>>(qw, n_layers, W1, Wq, bq, Wf, bf, ws_f, w1bf);
    fused_kernel<<<dim3(B/64), dim3(1024), 0, stream>>>(xq, U, ws_f, xc, w1bf, b1, Wf, out);
}

// Round 3
// 259.031 us; speedup vs baseline: 1.0453x; 1.0453x over previous
//
#include <hip/hip_runtime.h>
#include <hip/hip_bf16.h>

#define NQ 6

typedef __attribute__((ext_vector_type(8))) short short8;
typedef __attribute__((ext_vector_type(4))) float floatx4;

// ---------------- ws layout (bytes) ----------------
// U_circ : float2[64*64]        @ 0        (32768 B)
// Mq     : float[18]            @ 32768
// cq     : float[3]             @ 32840
// W1bf   : short[64*2048]       @ 36864    (262144 B)
#define WS_MQ_F   8192        // float offset of Mq
#define WS_CQ_F   (8192+18)
#define WS_W1BF_B 36864

// ============ K0: prep — U_circ columns, Mq/cq, W1->bf16 ============
__global__ __launch_bounds__(64) void prep_kernel(
    const float* __restrict__ qw, int n_layers,
    const float* __restrict__ W1, const float* __restrict__ Wq,
    const float* __restrict__ bq, const float* __restrict__ Wf,
    const float* __restrict__ bf, float* __restrict__ ws_f,
    short* __restrict__ w1bf)
{
    const int blk  = blockIdx.x;
    const int lane = threadIdx.x;

    if (blk == 0) {
        // Mq[j][w] = sum_m Wf[j][64+m] * Wq[m][w];  cq[j] = sum_m Wf[j][64+m]*bq[m] + bf[j]
        if (lane < 18) {
            int j = lane / 6, wi = lane % 6;
            float s = 0.f;
            for (int m = 0; m < 16; ++m) s += Wf[j*80 + 64 + m] * Wq[m*6 + wi];
            ws_f[WS_MQ_F + lane] = s;
        } else if (lane < 21) {
            int j = lane - 18;
            float s = bf[j];
            for (int m = 0; m < 16; ++m) s += Wf[j*80 + 64 + m] * bq[m];
            ws_f[WS_CQ_F + j] = s;
        }
    } else if (blk <= 64) {
        // U_circ column j: amplitudes-in-lanes, one wave
        const int j = blk - 1;
        float re = (lane == j) ? 1.f : 0.f;
        float im = 0.f;
        for (int l = 0; l < n_layers; ++l) {
            for (int w = 0; w < NQ; ++w) {
                const float* g = qw + (l*NQ + w)*3;
                float phi = g[0], th = g[1], om = g[2];
                float c, s;  __sincosf(0.5f*th, &s, &c);
                float sa, ca; __sincosf(0.5f*(phi+om), &sa, &ca);
                float sb, cb; __sincosf(0.5f*(phi-om), &sb, &cb);
                // U00=c(ca-i sa)  U01=-s(cb+i sb)  U10=s(cb-i sb)  U11=c(ca+i sa)
                float u00r =  c*ca, u00i = -c*sa;
                float u01r = -s*cb, u01i = -s*sb;
                float u10r =  s*cb, u10i = -s*sb;
                float u11r =  c*ca, u11i =  c*sa;
                int p = 5 - w, mask = 1 << p;
                float pre = __shfl_xor(re, mask, 64);
                float pim = __shfl_xor(im, mask, 64);
                int b = (lane >> p) & 1;
                float mr = b ? u11r : u00r, mi = b ? u11i : u00i;
                float pr = b ? u10r : u01r, pi = b ? u10i : u01i;
                float nre = mr*re - mi*im + pr*pre - pi*pim;
                float nim = mr*im + mi*re + pr*pim + pi*pre;
                re = nre; im = nim;
            }
            int r = l % (NQ-1) + 1;
            for (int w = 0; w < NQ; ++w) {
                int tgt = (w + r) % NQ;
                int tmask = 1 << (5 - tgt);
                float pre = __shfl_xor(re, tmask, 64);
                float pim = __shfl_xor(im, tmask, 64);
                int cs = (lane >> (5 - w)) & 1;
                re = cs ? pre : re;
                im = cs ? pim : im;
            }
        }
        ws_f[(lane*64 + j)*2 + 0] = re;   // U[i=lane][j].re
        ws_f[(lane*64 + j)*2 + 1] = im;
    } else {
        // W1 fp32 -> bf16 (same [n][k] row-major layout), blocks 65..320
        int idx = (blk - 65)*512 + lane*8;
        if (idx < 64*2048) {
            float4 a0 = *(const float4*)(W1 + idx);
            float4 a1 = *(const float4*)(W1 + idx + 4);
            union { short8 v; __hip_bfloat162 h[4]; } u;
            float2 f;
            f.x=a0.x; f.y=a0.y; u.h[0] = __float22bfloat162_rn(f);
            f.x=a0.z; f.y=a0.w; u.h[1] = __float22bfloat162_rn(f);
            f.x=a1.x; f.y=a1.y; u.h[2] = __float22bfloat162_rn(f);
            f.x=a1.z; f.y=a1.w; u.h[3] = __float22bfloat162_rn(f);
            *(short8*)(w1bf + idx) = u.v;
        }
    }
}

// ============ K1: fused quantum + GEMM + ReLU + 3-wide head ============
// grid B/64, 1024 threads (16 waves = 4 waves/SIMD). Phase Q uses the
// tensor-product factorization a[jh*8+jl] = ah[jh]*al[jl] -> 16 regs
// instead of 64 (R2's a[64] spilled at the 64-VGPR allocation).
// Phase G: wave (wr=t>>2, wc=t&3) computes a 16x16 quadrant, prefetch-1.
__global__ __launch_bounds__(1024) void fused_kernel(
    const float* __restrict__ xq, const float2* __restrict__ U,
    const float* __restrict__ ws_f,
    const float* __restrict__ xc, const short* __restrict__ w1bf,
    const float* __restrict__ b1, const float* __restrict__ Wf,
    float* __restrict__ out)
{
    const int tid  = threadIdx.x;
    const int lane = tid & 63;
    const int t    = __builtin_amdgcn_readfirstlane((int)(tid >> 6)); // wave 0..15
    const int blk  = blockIdx.x;

    __shared__ float zbuf[16][64][6];
    __shared__ float qres[64][3];
    __shared__ float cl[64][65];

    // ---------- Phase Q: quantum part for this block's 64 rows ----------
    {
        const int b = blk*64 + lane;
        const float* x = xq + (size_t)b*6;
        // factored product state: ah over qubits 0..2 (bits 5..3),
        // al over qubits 3..5 (bits 2..0); a[jh*8+jl] = ah[jh]*al[jl]
        float ah[8], al[8];
        ah[0] = 1.f;
        #pragma unroll
        for (int q = 0; q < 3; ++q) {
            float c, s; __sincosf(0.5f*x[q], &s, &c);
            const int sz = 1 << q;
            #pragma unroll
            for (int m = sz-1; m >= 0; --m) {
                float v = ah[m];
                ah[2*m+1] = v*s;
                ah[2*m+0] = v*c;
            }
        }
        al[0] = 1.f;
        #pragma unroll
        for (int q = 0; q < 3; ++q) {
            float c, s; __sincosf(0.5f*x[3+q], &s, &c);
            const int sz = 1 << q;
            #pragma unroll
            for (int m = sz-1; m >= 0; --m) {
                float v = al[m];
                al[2*m+1] = v*s;
                al[2*m+0] = v*c;
            }
        }

        float zp[6] = {0,0,0,0,0,0};
        const float2* Urow = U + t*4*64;   // wave-uniform -> scalar loads
        for (int ii = 0; ii < 4; ++ii) {
            float rr = 0.f, ri = 0.f;
            #pragma unroll
            for (int jh = 0; jh < 8; ++jh) {
                float sr = 0.f, si = 0.f;
                #pragma unroll
                for (int jl = 0; jl < 8; ++jl) {
                    float2 u = Urow[ii*64 + jh*8 + jl];
                    sr += u.x * al[jl];
                    si += u.y * al[jl];
                }
                rr += ah[jh] * sr;
                ri += ah[jh] * si;
            }
            float p = rr*rr + ri*ri;
            int i = t*4 + ii;
            #pragma unroll
            for (int w = 0; w < 6; ++w) zp[w] += ((i >> (5-w)) & 1) ? -p : p;
        }
        #pragma unroll
        for (int w = 0; w < 6; ++w) zbuf[t][lane][w] = zp[w];
    }
    __syncthreads();
    if (t == 0) {
        float z[6];
        #pragma unroll
        for (int w = 0; w < 6; ++w) {
            float s = 0.f;
            #pragma unroll
            for (int sbi = 0; sbi < 16; ++sbi) s += zbuf[sbi][lane][w];
            z[w] = s;
        }
        #pragma unroll
        for (int j = 0; j < 3; ++j) {
            float v = ws_f[WS_CQ_F + j];
            #pragma unroll
            for (int w = 0; w < 6; ++w) v += ws_f[WS_MQ_F + j*6 + w] * z[w];
            qres[lane][j] = v;
        }
    }
    // qres read only after the epilogue __syncthreads -> no extra sync.

    // ---------- Phase G: wave (wr,wc) -> rows [wr*16,+16) x cols [wc*16,+16) ----------
    const int wr = t >> 2, wc = t & 3;
    const int row  = blk*64 + wr*16 + (lane & 15);  // A fragment: m = lane&15
    const int koff = (lane >> 4) * 8;               // k = (lane>>4)*8 + j

    const float* ap = xc + (size_t)row*2048 + koff;
    const short* bp = w1bf + (wc*16 + (lane & 15))*2048 + koff;

    floatx4 acc = {0,0,0,0};

    // prologue loads (k-step 0)
    float4 a0 = *(const float4*)ap;
    float4 a1 = *(const float4*)(ap + 4);
    short8 bv = *(const short8*)bp;

    #pragma unroll 4
    for (int kk = 1; kk < 64; ++kk) {
        // issue next-iteration loads BEFORE consuming current registers
        float4 na0 = *(const float4*)(ap + kk*32);
        float4 na1 = *(const float4*)(ap + kk*32 + 4);
        short8 nbv = *(const short8*)(bp + kk*32);

        union { short8 v; __hip_bfloat162 h[4]; } af;
        float2 f;
        f.x=a0.x; f.y=a0.y; af.h[0] = __float22bfloat162_rn(f);
        f.x=a0.z; f.y=a0.w; af.h[1] = __float22bfloat162_rn(f);
        f.x=a1.x; f.y=a1.y; af.h[2] = __float22bfloat162_rn(f);
        f.x=a1.z; f.y=a1.w; af.h[3] = __float22bfloat162_rn(f);

        acc = __builtin_amdgcn_mfma_f32_16x16x32_bf16(af.v, bv, acc, 0, 0, 0);

        a0 = na0; a1 = na1; bv = nbv;
    }
    {   // tail (k-step 63's registers)
        union { short8 v; __hip_bfloat162 h[4]; } af;
        float2 f;
        f.x=a0.x; f.y=a0.y; af.h[0] = __float22bfloat162_rn(f);
        f.x=a0.z; f.y=a0.w; af.h[1] = __float22bfloat162_rn(f);
        f.x=a1.x; f.y=a1.y; af.h[2] = __float22bfloat162_rn(f);
        f.x=a1.z; f.y=a1.w; af.h[3] = __float22bfloat162_rn(f);
        acc = __builtin_amdgcn_mfma_f32_16x16x32_bf16(af.v, bv, acc, 0, 0, 0);
    }

    // epilogue: C layout col = wc*16 + (lane&15), row = wr*16 + (lane>>4)*4 + r
    const int rbase = wr*16 + ((lane >> 4) * 4);
    const int c0 = wc*16 + (lane & 15);
    const float bb = b1[c0];
    #pragma unroll
    for (int r = 0; r < 4; ++r)
        cl[rbase + r][c0] = fmaxf(acc[r] + bb, 0.f);
    __syncthreads();

    // final head: wave j (0..2) handles output column j for all 64 rows
    const int rr2 = tid & 63;
    if (t < 3) {
        float v = 0.f;
        #pragma unroll
        for (int col = 0; col < 64; ++col) v += Wf[t*80 + col] * cl[rr2][col];
        int g = blk*64 + rr2;
        out[(size_t)g*3 + t] = v + qres[rr2][t];
    }
}

extern "C" void kernel_launch(void* const* d_in, const int* in_sizes, int n_in,
                              void* d_out, int out_size, void* d_ws, size_t ws_size,
                              hipStream_t stream) {
    const float* xc = (const float*)d_in[0];
    const float* xq = (const float*)d_in[1];
    const float* W1 = (const float*)d_in[2];
    const float* b1 = (const float*)d_in[3];
    const float* qw = (const float*)d_in[4];
    const float* Wq = (const float*)d_in[5];
    const float* bq = (const float*)d_in[6];
    const float* Wf = (const float*)d_in[7];
    const float* bf = (const float*)d_in[8];
    float* out = (float*)d_out;

    const int B = in_sizes[1] / NQ;                 // 16384
    const int n_layers = in_sizes[4] / (NQ * 3);    // 3

    char* ws = (char*)d_ws;
    float*  ws_f  = (float*)ws;
    float2* U     = (float2*)ws;
    short*  w1bf  = (short*)(ws + WS_W1BF_B);

    prep_kernel<<<dim3(321), dim3(64), 0, stream>>>(qw, n_layers, W1, Wq, bq, Wf, bf, ws_f, w1bf);
    fused_kernel<<<dim3(B/64), dim3(1024), 0, stream>>>(xq, U, ws_f, xc, w1bf, b1, Wf, out);
}

// Round 4
// 219.730 us; speedup vs baseline: 1.2323x; 1.1789x over previous
//
#include <hip/hip_runtime.h>
#include <hip/hip_bf16.h>

#define NQ 6

typedef __attribute__((ext_vector_type(8))) short short8;
typedef __attribute__((ext_vector_type(4))) float floatx4;

// ---------------- ws layout (bytes) ----------------
// U_circ : float2[64*64]        @ 0        (32768 B)
// Mq     : float[18]            @ 32768
// cq     : float[3]             @ 32840
// W1bf   : short[64*2048]       @ 36864    (262144 B)
#define WS_MQ_F   8192        // float offset of Mq
#define WS_CQ_F   (8192+18)
#define WS_W1BF_B 36864

// ============ K0: prep — U_circ columns, Mq/cq, W1->bf16 ============
__global__ __launch_bounds__(64) void prep_kernel(
    const float* __restrict__ qw, int n_layers,
    const float* __restrict__ W1, const float* __restrict__ Wq,
    const float* __restrict__ bq, const float* __restrict__ Wf,
    const float* __restrict__ bf, float* __restrict__ ws_f,
    short* __restrict__ w1bf)
{
    const int blk  = blockIdx.x;
    const int lane = threadIdx.x;

    if (blk == 0) {
        if (lane < 18) {
            int j = lane / 6, wi = lane % 6;
            float s = 0.f;
            for (int m = 0; m < 16; ++m) s += Wf[j*80 + 64 + m] * Wq[m*6 + wi];
            ws_f[WS_MQ_F + lane] = s;
        } else if (lane < 21) {
            int j = lane - 18;
            float s = bf[j];
            for (int m = 0; m < 16; ++m) s += Wf[j*80 + 64 + m] * bq[m];
            ws_f[WS_CQ_F + j] = s;
        }
    } else if (blk <= 64) {
        // U_circ column j: amplitudes-in-lanes, one wave
        const int j = blk - 1;
        float re = (lane == j) ? 1.f : 0.f;
        float im = 0.f;
        for (int l = 0; l < n_layers; ++l) {
            for (int w = 0; w < NQ; ++w) {
                const float* g = qw + (l*NQ + w)*3;
                float phi = g[0], th = g[1], om = g[2];
                float c, s;  __sincosf(0.5f*th, &s, &c);
                float sa, ca; __sincosf(0.5f*(phi+om), &sa, &ca);
                float sb, cb; __sincosf(0.5f*(phi-om), &sb, &cb);
                float u00r =  c*ca, u00i = -c*sa;
                float u01r = -s*cb, u01i = -s*sb;
                float u10r =  s*cb, u10i = -s*sb;
                float u11r =  c*ca, u11i =  c*sa;
                int p = 5 - w, mask = 1 << p;
                float pre = __shfl_xor(re, mask, 64);
                float pim = __shfl_xor(im, mask, 64);
                int b = (lane >> p) & 1;
                float mr = b ? u11r : u00r, mi = b ? u11i : u00i;
                float pr = b ? u10r : u01r, pi = b ? u10i : u01i;
                float nre = mr*re - mi*im + pr*pre - pi*pim;
                float nim = mr*im + mi*re + pr*pim + pi*pre;
                re = nre; im = nim;
            }
            int r = l % (NQ-1) + 1;
            for (int w = 0; w < NQ; ++w) {
                int tgt = (w + r) % NQ;
                int tmask = 1 << (5 - tgt);
                float pre = __shfl_xor(re, tmask, 64);
                float pim = __shfl_xor(im, tmask, 64);
                int cs = (lane >> (5 - w)) & 1;
                re = cs ? pre : re;
                im = cs ? pim : im;
            }
        }
        ws_f[(lane*64 + j)*2 + 0] = re;   // U[i=lane][j].re
        ws_f[(lane*64 + j)*2 + 1] = im;
    } else {
        // W1 fp32 -> bf16 (row-major [n][k]), blocks 65..320
        int idx = (blk - 65)*512 + lane*8;
        if (idx < 64*2048) {
            float4 a0 = *(const float4*)(W1 + idx);
            float4 a1 = *(const float4*)(W1 + idx + 4);
            union { short8 v; __hip_bfloat162 h[4]; } u;
            float2 f;
            f.x=a0.x; f.y=a0.y; u.h[0] = __float22bfloat162_rn(f);
            f.x=a0.z; f.y=a0.w; u.h[1] = __float22bfloat162_rn(f);
            f.x=a1.x; f.y=a1.y; u.h[2] = __float22bfloat162_rn(f);
            f.x=a1.z; f.y=a1.w; u.h[3] = __float22bfloat162_rn(f);
            *(short8*)(w1bf + idx) = u.v;
        }
    }
}

__device__ __forceinline__ short8 cvt_bf16x8(float4 a0, float4 a1) {
    union { short8 v; __hip_bfloat162 h[4]; } u;
    float2 f;
    f.x=a0.x; f.y=a0.y; u.h[0] = __float22bfloat162_rn(f);
    f.x=a0.z; f.y=a0.w; u.h[1] = __float22bfloat162_rn(f);
    f.x=a1.x; f.y=a1.y; u.h[2] = __float22bfloat162_rn(f);
    f.x=a1.z; f.y=a1.w; u.h[3] = __float22bfloat162_rn(f);
    return u.v;
}

// ============ K1: fused quantum + GEMM + ReLU + 3-wide head ============
// grid B/64, 1024 threads (16 waves). K=2048 split into 16 chunks of 128.
// A staged cooperatively: global->reg (issued 2 chunks ahead) ->bf16->
// swizzled LDS (double-buffered). Wave (wr,wc) does 4 MFMA per chunk from
// LDS; B prefetched 1 chunk ahead in regs. In-flight ~64KB/CU.
__global__ __launch_bounds__(1024) void fused_kernel(
    const float* __restrict__ xq, const float2* __restrict__ U,
    const float* __restrict__ ws_f,
    const float* __restrict__ xc, const short* __restrict__ w1bf,
    const float* __restrict__ b1, const float* __restrict__ Wf,
    float* __restrict__ out)
{
    const int tid  = threadIdx.x;
    const int lane = tid & 63;
    const int t    = __builtin_amdgcn_readfirstlane((int)(tid >> 6)); // wave 0..15
    const int blk  = blockIdx.x;

    __shared__ __align__(16) short Abuf[2][64*128];  // bf16, swizzled slots
    __shared__ float zbuf[16][64][6];
    __shared__ float qres[64][3];
    __shared__ float cl[64][65];

    // ---- addressing ----
    const int wr = t >> 2, wc = t & 3;
    // stage (writer) side: thread -> (row, 8-float group)
    const int srow = tid >> 4;          // 0..63
    const int sgrp = tid & 15;          // 0..15
    const float* asrc = xc + (size_t)(blk*64 + srow)*2048 + sgrp*8;
    const int adoff = srow*128 + ((sgrp ^ (srow & 7)) << 3);   // shorts
    // fragment (reader) side
    const int arow = wr*16 + (lane & 15);
    const int abase = arow*128;
    const int arx = arow & 7;
    const int a_l = lane >> 4;          // 0..3
    // B side
    const short* bp = w1bf + (wc*16 + (lane & 15))*2048 + a_l*8;

    // ---- load xq FIRST so Phase Q's waitcnt doesn't drain the pipeline ----
    const float* xrow = xq + (size_t)(blk*64 + lane)*6;
    float2 xq01 = *(const float2*)(xrow);
    float2 xq23 = *(const float2*)(xrow + 2);
    float2 xq45 = *(const float2*)(xrow + 4);

    // ---- prologue issues: A chunks 0,1 and B chunk 0 ----
    float4 sA0[2], sA1[2];
    sA0[0] = *(const float4*)(asrc + 0*128);
    sA1[0] = *(const float4*)(asrc + 0*128 + 4);
    sA0[1] = *(const float4*)(asrc + 1*128);
    sA1[1] = *(const float4*)(asrc + 1*128 + 4);
    short8 bv0 = *(const short8*)(bp + 0);
    short8 bv1 = *(const short8*)(bp + 32);
    short8 bv2 = *(const short8*)(bp + 64);
    short8 bv3 = *(const short8*)(bp + 96);

    // ---------- Phase Q (overlaps with prologue loads in flight) ----------
    {
        const float xs[6] = {xq01.x, xq01.y, xq23.x, xq23.y, xq45.x, xq45.y};
        float ah[8], al[8];
        ah[0] = 1.f;
        #pragma unroll
        for (int q = 0; q < 3; ++q) {
            float c, s; __sincosf(0.5f*xs[q], &s, &c);
            const int sz = 1 << q;
            #pragma unroll
            for (int m = sz-1; m >= 0; --m) {
                float v = ah[m];
                ah[2*m+1] = v*s;
                ah[2*m+0] = v*c;
            }
        }
        al[0] = 1.f;
        #pragma unroll
        for (int q = 0; q < 3; ++q) {
            float c, s; __sincosf(0.5f*xs[3+q], &s, &c);
            const int sz = 1 << q;
            #pragma unroll
            for (int m = sz-1; m >= 0; --m) {
                float v = al[m];
                al[2*m+1] = v*s;
                al[2*m+0] = v*c;
            }
        }

        float zp[6] = {0,0,0,0,0,0};
        const float2* Urow = U + t*4*64;   // wave-uniform -> scalar loads
        for (int ii = 0; ii < 4; ++ii) {
            float rr = 0.f, ri = 0.f;
            #pragma unroll
            for (int jh = 0; jh < 8; ++jh) {
                float sr = 0.f, si = 0.f;
                #pragma unroll
                for (int jl = 0; jl < 8; ++jl) {
                    float2 u = Urow[ii*64 + jh*8 + jl];
                    sr += u.x * al[jl];
                    si += u.y * al[jl];
                }
                rr += ah[jh] * sr;
                ri += ah[jh] * si;
            }
            float p = rr*rr + ri*ri;
            int i = t*4 + ii;
            #pragma unroll
            for (int w = 0; w < 6; ++w) zp[w] += ((i >> (5-w)) & 1) ? -p : p;
        }
        #pragma unroll
        for (int w = 0; w < 6; ++w) zbuf[t][lane][w] = zp[w];
    }
    __syncthreads();
    if (t == 0) {
        float z[6];
        #pragma unroll
        for (int w = 0; w < 6; ++w) {
            float s = 0.f;
            #pragma unroll
            for (int sbi = 0; sbi < 16; ++sbi) s += zbuf[sbi][lane][w];
            z[w] = s;
        }
        #pragma unroll
        for (int j = 0; j < 3; ++j) {
            float v = ws_f[WS_CQ_F + j];
            #pragma unroll
            for (int w = 0; w < 6; ++w) v += ws_f[WS_MQ_F + j*6 + w] * z[w];
            qres[lane][j] = v;
        }
    }

    // ---------- Phase G ----------
    // write chunk 0 into buf 0
    *(short8*)(&Abuf[0][adoff]) = cvt_bf16x8(sA0[0], sA1[0]);
    __syncthreads();   // buf0 ready (also covers qres/zbuf ordering)

    floatx4 acc = {0,0,0,0};

    #pragma unroll
    for (int c = 0; c < 16; ++c) {
        const int cb = c & 1;

        // issue A loads for chunk c+2 (set cb was flushed to LDS already)
        if (c + 2 < 16) {
            sA0[cb] = *(const float4*)(asrc + (c+2)*128);
            sA1[cb] = *(const float4*)(asrc + (c+2)*128 + 4);
        }
        // issue B loads for chunk c+1
        short8 nb0, nb1, nb2, nb3;
        if (c + 1 < 16) {
            nb0 = *(const short8*)(bp + (c+1)*128 + 0);
            nb1 = *(const short8*)(bp + (c+1)*128 + 32);
            nb2 = *(const short8*)(bp + (c+1)*128 + 64);
            nb3 = *(const short8*)(bp + (c+1)*128 + 96);
        }

        // compute: 4 k-steps from Abuf[cb]
        const short* abp = &Abuf[cb][abase];
        short8 av0 = *(const short8*)(abp + ((((0*4 + a_l)) ^ arx) << 3));
        short8 av1 = *(const short8*)(abp + ((((1*4 + a_l)) ^ arx) << 3));
        short8 av2 = *(const short8*)(abp + ((((2*4 + a_l)) ^ arx) << 3));
        short8 av3 = *(const short8*)(abp + ((((3*4 + a_l)) ^ arx) << 3));
        acc = __builtin_amdgcn_mfma_f32_16x16x32_bf16(av0, bv0, acc, 0, 0, 0);
        acc = __builtin_amdgcn_mfma_f32_16x16x32_bf16(av1, bv1, acc, 0, 0, 0);
        acc = __builtin_amdgcn_mfma_f32_16x16x32_bf16(av2, bv2, acc, 0, 0, 0);
        acc = __builtin_amdgcn_mfma_f32_16x16x32_bf16(av3, bv3, acc, 0, 0, 0);

        // flush chunk c+1 (issued at c-1, landed by now) into buf cb^1
        if (c + 1 < 16) {
            *(short8*)(&Abuf[cb ^ 1][adoff]) = cvt_bf16x8(sA0[cb ^ 1], sA1[cb ^ 1]);
            bv0 = nb0; bv1 = nb1; bv2 = nb2; bv3 = nb3;
            __syncthreads();   // buf cb^1 ready for chunk c+1
        }
    }

    // epilogue: C layout col = wc*16 + (lane&15), row = wr*16 + (lane>>4)*4 + r
    const int rbase = wr*16 + (a_l * 4);
    const int c0 = wc*16 + (lane & 15);
    const float bb = b1[c0];
    #pragma unroll
    for (int r = 0; r < 4; ++r)
        cl[rbase + r][c0] = fmaxf(acc[r] + bb, 0.f);
    __syncthreads();

    // final head: wave j (0..2) handles output column j for all 64 rows
    const int rr2 = tid & 63;
    if (t < 3) {
        float v = 0.f;
        #pragma unroll
        for (int col = 0; col < 64; ++col) v += Wf[t*80 + col] * cl[rr2][col];
        int g = blk*64 + rr2;
        out[(size_t)g*3 + t] = v + qres[rr2][t];
    }
}

extern "C" void kernel_launch(void* const* d_in, const int* in_sizes, int n_in,
                              void* d_out, int out_size, void* d_ws, size_t ws_size,
                              hipStream_t stream) {
    const float* xc = (const float*)d_in[0];
    const float* xq = (const float*)d_in[1];
    const float* W1 = (const float*)d_in[2];
    const float* b1 = (const float*)d_in[3];
    const float* qw = (const float*)d_in[4];
    const float* Wq = (const float*)d_in[5];
    const float* bq = (const float*)d_in[6];
    const float* Wf = (const float*)d_in[7];
    const float* bf = (const float*)d_in[8];
    float* out = (float*)d_out;

    const int B = in_sizes[1] / NQ;                 // 16384
    const int n_layers = in_sizes[4] / (NQ * 3);    // 3

    char* ws = (char*)d_ws;
    float*  ws_f  = (float*)ws;
    float2* U     = (float2*)ws;
    short*  w1bf  = (short*)(ws + WS_W1BF_B);

    prep_kernel<<<dim3(321), dim3(64), 0, stream>>>(qw, n_layers, W1, Wq, bq, Wf, bf, ws_f, w1bf);
    fused_kernel<<<dim3(B/64), dim3(1024), 0, stream>>>(xq, U, ws_f, xc, w1bf, b1, Wf, out);
}